// Round 2
// baseline (995.114 us; speedup 1.0000x reference)
//
#include <hip/hip_runtime.h>

#define NQ 14
#define NL 6
#define DIM (1 << NQ)   // 16384 amplitudes
#define TPB 256

// ---------------------------------------------------------------------------
// Compile-time tables: per-layer entangler permutation (folded CNOTs).
// Logical index i (14 bits, wire w <-> bit 13-w). CNOT(c_bit, g_bit) acts as
// j -> j ^ (j_c ? e_g : 0), matrix M = I + e_g e_c^T. Layer perm
// Pi = M_0 * M_1 * ... * M_13 (application order). After each layer's last
// pass we write amp (currently at index h) to j = Pi^{-1} h, so storage stays
// identity-mapped. LDS addresses carry swizzle s(h) = h ^ ((h>>6)&63).
// ---------------------------------------------------------------------------
struct Tbl {
    unsigned short Wt[NL][256];
    unsigned short Wk[NL][64];
};

constexpr Tbl buildTbl() {
    Tbl T{};
    for (int l = 0; l < NL; ++l) {
        const int rng = l + 1;   // entangler range r = (l % (NQ-1)) + 1
        // Pi columns (col[p] = Pi * e_p), built by sequential right-mult
        unsigned short col[NQ] = {};
        for (int p = 0; p < NQ; ++p) col[p] = (unsigned short)(1 << p);
        for (int w = 0; w < NQ; ++w) {
            int c = NQ - 1 - w;
            int g = NQ - 1 - ((w + rng) % NQ);
            col[c] ^= col[g];
        }
        // invert Pi via Gauss-Jordan on rows
        unsigned int M[NQ] = {}, Inv[NQ] = {};
        for (int q = 0; q < NQ; ++q) {
            M[q] = 0;
            for (int p = 0; p < NQ; ++p) M[q] |= (unsigned)((col[p] >> q) & 1) << p;
            Inv[q] = 1u << q;
        }
        for (int cp = 0; cp < NQ; ++cp) {
            int piv = cp;
            while (!((M[piv] >> cp) & 1)) ++piv;
            unsigned tmp = M[piv]; M[piv] = M[cp]; M[cp] = tmp;
            tmp = Inv[piv]; Inv[piv] = Inv[cp]; Inv[cp] = tmp;
            for (int q = 0; q < NQ; ++q)
                if (q != cp && ((M[q] >> cp) & 1)) { M[q] ^= M[cp]; Inv[q] ^= Inv[cp]; }
        }
        // columns of Pi^{-1}
        unsigned short colInv[NQ] = {};
        for (int p = 0; p < NQ; ++p) {
            unsigned short v = 0;
            for (int q = 0; q < NQ; ++q) v |= (unsigned short)(((Inv[q] >> p) & 1) << q);
            colInv[p] = v;
        }
        // pass-2 coset shapes: thread bits -> logical {6,7,8,9,4,5,10,11},
        // block bits -> logical {12,13,0,1,2,3}
        for (int t = 0; t < 256; ++t) {
            int ht = ((t & 15) << 6) | (((t >> 4) & 3) << 4) | (((t >> 6) & 3) << 10);
            int r2 = 0;
            for (int p = 0; p < NQ; ++p) if ((ht >> p) & 1) r2 ^= colInv[p];
            T.Wt[l][t] = (unsigned short)(r2 ^ ((r2 >> 6) & 63));
        }
        for (int k = 0; k < 64; ++k) {
            int hk = ((k & 3) << 12) | ((k >> 2) & 15);
            int r2 = 0;
            for (int p = 0; p < NQ; ++p) if ((hk >> p) & 1) r2 ^= colInv[p];
            T.Wk[l][k] = (unsigned short)(r2 ^ ((r2 >> 6) & 63));
        }
    }
    return T;
}

__device__ const Tbl dT = buildTbl();

__device__ __forceinline__ int swz(int h) { return h ^ ((h >> 6) & 63); }

template <int S>
__device__ __forceinline__ int haddr(int t, int k) {
    int h;
    if constexpr (S == 0) {
        h = (t << 6) | k;                               // k -> bits 0..5, t -> 6..13
    } else if constexpr (S == 1) {
        h = (t & 63) | (k << 6) | ((t >> 6) << 12);     // k -> bits 6..11
    } else {
        h = ((t & 15) << 6) | (((t >> 4) & 3) << 4) | (((t >> 6) & 3) << 10)
          | ((k & 3) << 12) | ((k >> 2) & 15);          // k bits 0,1 -> 12,13
    }
    return swz(h);
}

__device__ __forceinline__ void gate2(float2 u0, float2 u1, float2 u2, float2 u3,
                                      float2& A, float2& C) {
    float2 a = A, c = C, na, nc;
    na.x = u0.x * a.x - u0.y * a.y + u1.x * c.x - u1.y * c.y;
    na.y = u0.x * a.y + u0.y * a.x + u1.x * c.y + u1.y * c.x;
    nc.x = u2.x * a.x - u2.y * a.y + u3.x * c.x - u3.y * c.y;
    nc.y = u2.x * a.y + u2.y * a.x + u3.x * c.y + u3.y * c.x;
    A = na; C = nc;
}

template <int S>
__device__ __forceinline__ void doPass(float2* st, const float2 (*U)[4], int l, int t,
                                       const unsigned short* wt, const unsigned short* wk) {
    float2 r[64];
#pragma unroll
    for (int k = 0; k < 64; ++k) r[k] = st[haddr<S>(t, k)];

    if constexpr (S == 2) __syncthreads();   // all reads done before permuted writes

    constexpr int NG = (S == 2) ? 2 : 6;
#pragma unroll
    for (int j = 0; j < NG; ++j) {
        const int w = (S == 0) ? (13 - j) : ((S == 1) ? (7 - j) : (1 - j));
        const float2* u = U[l * NQ + w];
        float2 u0 = u[0], u1 = u[1], u2 = u[2], u3 = u[3];
#pragma unroll
        for (int m = 0; m < 32; ++m) {
            const int k0 = ((m >> j) << (j + 1)) | (m & ((1 << j) - 1));
            gate2(u0, u1, u2, u3, r[k0], r[k0 | (1 << j)]);
        }
    }

    if constexpr (S == 2) {
        const int at = wt[t];
#pragma unroll
        for (int k = 0; k < 64; ++k) st[at ^ wk[k]] = r[k];
    } else {
#pragma unroll
        for (int k = 0; k < 64; ++k) st[haddr<S>(t, k)] = r[k];
    }
}

__global__ __launch_bounds__(TPB, 1)
void qc_kernel(const float* __restrict__ x,
               const float* __restrict__ wts,
               const float* __restrict__ fcw,
               const float* __restrict__ fcb,
               float* __restrict__ out)
{
    extern __shared__ float2 st[];           // DIM float2 = 128 KiB (swizzled layout)
    __shared__ float2 U[NL * NQ][4];         // Rot (layer0: Rot*RX) matrices
    __shared__ float2 R[NQ][4];              // RX matrices (temp)
    __shared__ float wsum[TPB / 64];

    const int b = blockIdx.x;
    const int t = threadIdx.x;

    // zero state
    for (int i = t; i < DIM; i += TPB) st[i] = make_float2(0.f, 0.f);

    // gate matrices
    if (t < NQ) {
        float th = 0.5f * x[b * NQ + t];
        float c = cosf(th), s = sinf(th);
        R[t][0] = make_float2(c, 0.f);
        R[t][1] = make_float2(0.f, -s);
        R[t][2] = make_float2(0.f, -s);
        R[t][3] = make_float2(c, 0.f);
    }
    if (t >= 64 && t < 64 + NL * NQ) {
        int g = t - 64;
        float phi = wts[g * 3 + 0];
        float th  = wts[g * 3 + 1];
        float om  = wts[g * 3 + 2];
        float c = cosf(0.5f * th), s = sinf(0.5f * th);
        float aa = 0.5f * (phi + om), dd = 0.5f * (phi - om);
        float ca = cosf(aa), sa = sinf(aa);
        float cd = cosf(dd), sd = sinf(dd);
        U[g][0] = make_float2( ca * c, -sa * c);
        U[g][1] = make_float2(-cd * s, -sd * s);
        U[g][2] = make_float2( cd * s, -sd * s);
        U[g][3] = make_float2( ca * c,  sa * c);
    }
    __syncthreads();

    // fold RX into layer-0 Rot: U0 = Rot * RX
    if (t < NQ) {
        float2 a00 = U[t][0], a01 = U[t][1], a10 = U[t][2], a11 = U[t][3];
        float2 b00 = R[t][0], b01 = R[t][1], b10 = R[t][2], b11 = R[t][3];
        auto cm = [](float2 p, float2 q) {
            return make_float2(p.x * q.x - p.y * q.y, p.x * q.y + p.y * q.x);
        };
        auto ca2 = [](float2 p, float2 q) { return make_float2(p.x + q.x, p.y + q.y); };
        U[t][0] = ca2(cm(a00, b00), cm(a01, b10));
        U[t][1] = ca2(cm(a00, b01), cm(a01, b11));
        U[t][2] = ca2(cm(a10, b00), cm(a11, b10));
        U[t][3] = ca2(cm(a10, b01), cm(a11, b11));
    }
    if (t == 0) st[0] = make_float2(1.f, 0.f);   // swz(0)==0
    __syncthreads();

    // ---- 6 layers x 3 fused passes; entangler folded into pass-2 write ----
    for (int l = 0; l < NL; ++l) {
        doPass<0>(st, U, l, t, nullptr, nullptr);
        __syncthreads();
        doPass<1>(st, U, l, t, nullptr, nullptr);
        __syncthreads();
        doPass<2>(st, U, l, t, dT.Wt[l], dT.Wk[l]);
        __syncthreads();
    }

    // ---- fused expectation + FC (storage is identity-mapped, swizzled) ----
    float fw[NQ];
#pragma unroll
    for (int w = 0; w < NQ; ++w) fw[w] = fcw[w];

    float gl = 0.f;
#pragma unroll
    for (int w = 6; w < NQ; ++w) gl += ((t >> (13 - w)) & 1) ? -fw[w] : fw[w];

    float acc = 0.f;
#pragma unroll
    for (int n = 0; n < 64; ++n) {
        float2 a = st[swz((n << 8) | t)];
        float p = a.x * a.x + a.y * a.y;
        float g = gl;
#pragma unroll
        for (int w = 0; w < 6; ++w) g += ((n >> (5 - w)) & 1) ? -fw[w] : fw[w];
        acc = fmaf(p, g, acc);
    }

#pragma unroll
    for (int off = 32; off > 0; off >>= 1) acc += __shfl_down(acc, off, 64);
    if ((t & 63) == 0) wsum[t >> 6] = acc;
    __syncthreads();
    if (t == 0) {
        float s = 0.f;
#pragma unroll
        for (int wv = 0; wv < TPB / 64; ++wv) s += wsum[wv];
        out[b] = s + fcb[0];
    }
}

extern "C" void kernel_launch(void* const* d_in, const int* in_sizes, int n_in,
                              void* d_out, int out_size, void* d_ws, size_t ws_size,
                              hipStream_t stream)
{
    const float* x   = (const float*)d_in[0];   // (512, 14)
    const float* wts = (const float*)d_in[1];   // (6, 14, 3)
    const float* fcw = (const float*)d_in[2];   // (1, 14)
    const float* fcb = (const float*)d_in[3];   // (1,)
    float* out = (float*)d_out;                 // (512,)

    const int batch = in_sizes[0] / NQ;         // 512
    const size_t lds_bytes = (size_t)DIM * sizeof(float2);  // 131072

    static bool attr_set = false;
    if (!attr_set) {
        (void)hipFuncSetAttribute((const void*)qc_kernel,
                                  hipFuncAttributeMaxDynamicSharedMemorySize,
                                  (int)lds_bytes);
        attr_set = true;
    }

    qc_kernel<<<batch, TPB, lds_bytes, stream>>>(x, wts, fcw, fcb, out);
}

// Round 3
// 437.086 us; speedup vs baseline: 2.2767x; 2.2767x over previous
//
#include <hip/hip_runtime.h>

#define NQ 14
#define NL 6
#define DIM (1 << NQ)   // 16384 amplitudes
#define TPB 512

// ---------------------------------------------------------------------------
// One block (512 thr) per sample; state in 128 KiB dynamic LDS (swizzled).
// 3 fused passes per layer (5+5+4 gate bits), 32 amps in registers per thread.
// The CNOT entangler layer is a GF(2)-linear index permutation folded into
// pass-2's writeback via compile-time tables (verified exact in round 2).
// ---------------------------------------------------------------------------
struct Tbl {
    unsigned short Wt[NL][TPB];
    unsigned short Wk[NL][32];
};

constexpr Tbl buildTbl() {
    Tbl T{};
    for (int l = 0; l < NL; ++l) {
        const int rng = l + 1;   // entangler range r = (l % (NQ-1)) + 1
        // accumulate layer permutation Pi (columns), same construction that
        // passed bit-exact in round 2
        unsigned short col[NQ] = {};
        for (int p = 0; p < NQ; ++p) col[p] = (unsigned short)(1 << p);
        for (int w = 0; w < NQ; ++w) {
            int c = NQ - 1 - w;
            int g = NQ - 1 - ((w + rng) % NQ);
            col[c] ^= col[g];
        }
        // invert via Gauss-Jordan
        unsigned int M[NQ] = {}, Inv[NQ] = {};
        for (int q = 0; q < NQ; ++q) {
            M[q] = 0;
            for (int p = 0; p < NQ; ++p) M[q] |= (unsigned)((col[p] >> q) & 1) << p;
            Inv[q] = 1u << q;
        }
        for (int cp = 0; cp < NQ; ++cp) {
            int piv = cp;
            while (!((M[piv] >> cp) & 1)) ++piv;
            unsigned tmp = M[piv]; M[piv] = M[cp]; M[cp] = tmp;
            tmp = Inv[piv]; Inv[piv] = Inv[cp]; Inv[cp] = tmp;
            for (int q = 0; q < NQ; ++q)
                if (q != cp && ((M[q] >> cp) & 1)) { M[q] ^= M[cp]; Inv[q] ^= Inv[cp]; }
        }
        unsigned short colInv[NQ] = {};
        for (int p = 0; p < NQ; ++p) {
            unsigned short v = 0;
            for (int q = 0; q < NQ; ++q) v |= (unsigned short)(((Inv[q] >> p) & 1) << q);
            colInv[p] = v;
        }
        // pass-2 coset shapes (TPB=512, 32 amps):
        //   t bits 0..3 -> h bits 0..3, t bits 4..8 -> h bits 5..9
        //   k bit 0 -> h bit 4, k bits 1..4 -> h bits 10..13
        for (int t = 0; t < TPB; ++t) {
            int ht = (t & 15) | (((t >> 4) & 31) << 5);
            int r2 = 0;
            for (int p = 0; p < NQ; ++p) if ((ht >> p) & 1) r2 ^= colInv[p];
            T.Wt[l][t] = (unsigned short)(r2 ^ ((r2 >> 6) & 63));
        }
        for (int k = 0; k < 32; ++k) {
            int hk = ((k & 1) << 4) | ((k >> 1) << 10);
            int r2 = 0;
            for (int p = 0; p < NQ; ++p) if ((hk >> p) & 1) r2 ^= colInv[p];
            T.Wk[l][k] = (unsigned short)(r2 ^ ((r2 >> 6) & 63));
        }
    }
    return T;
}

__device__ const Tbl dT = buildTbl();

__device__ __forceinline__ int swz(int h) { return h ^ ((h >> 6) & 63); }

template <int S>
__device__ __forceinline__ int haddr(int t, int k) {
    int h;
    if constexpr (S == 0) {
        h = (t << 5) | k;                                        // k -> bits 0..4
    } else if constexpr (S == 1) {
        h = (t & 31) | (k << 5) | ((t >> 5) << 10);              // k -> bits 5..9
    } else {
        h = (t & 15) | (((t >> 4) & 31) << 5)
          | ((k & 1) << 4) | ((k >> 1) << 10);                   // k bits 1..4 -> 10..13
    }
    return swz(h);
}

__device__ __forceinline__ void gate2(float2 u0, float2 u1, float2 u2, float2 u3,
                                      float2& A, float2& C) {
    float2 a = A, c = C, na, nc;
    na.x = u0.x * a.x - u0.y * a.y + u1.x * c.x - u1.y * c.y;
    na.y = u0.x * a.y + u0.y * a.x + u1.x * c.y + u1.y * c.x;
    nc.x = u2.x * a.x - u2.y * a.y + u3.x * c.x - u3.y * c.y;
    nc.y = u2.x * a.y + u2.y * a.x + u3.x * c.y + u3.y * c.x;
    A = na; C = nc;
}

template <int S>
__device__ __forceinline__ void doPass(float2* st, const float2 (*U)[4], int l, int t,
                                       const unsigned short* wt, const unsigned short* wk) {
    float2 r[32];
#pragma unroll
    for (int k = 0; k < 32; ++k) r[k] = st[haddr<S>(t, k)];

    if constexpr (S == 2) __syncthreads();   // all reads done before permuted writes

    constexpr int NG = (S == 2) ? 4 : 5;
#pragma unroll
    for (int jj = 0; jj < NG; ++jj) {
        const int j = (S == 2) ? (jj + 1) : jj;                  // k-bit of this gate
        const int w = (S == 0) ? (13 - jj) : ((S == 1) ? (8 - jj) : (3 - jj));
        const float2* u = U[l * NQ + w];
        float2 u0 = u[0], u1 = u[1], u2 = u[2], u3 = u[3];
#pragma unroll
        for (int m = 0; m < 16; ++m) {
            const int k0 = ((m >> j) << (j + 1)) | (m & ((1 << j) - 1));
            gate2(u0, u1, u2, u3, r[k0], r[k0 | (1 << j)]);
        }
    }

    if constexpr (S == 2) {
        const int at = wt[t];
#pragma unroll
        for (int k = 0; k < 32; ++k) st[at ^ wk[k]] = r[k];
    } else {
#pragma unroll
        for (int k = 0; k < 32; ++k) st[haddr<S>(t, k)] = r[k];
    }
}

__global__ __launch_bounds__(TPB, 2)
void qc_kernel(const float* __restrict__ x,
               const float* __restrict__ wts,
               const float* __restrict__ fcw,
               const float* __restrict__ fcb,
               float* __restrict__ out)
{
    extern __shared__ float2 st[];           // DIM float2 = 128 KiB (swizzled layout)
    __shared__ float2 U[NL * NQ][4];         // Rot (layer0: Rot*RX) matrices
    __shared__ float2 R[NQ][4];              // RX matrices (temp)
    __shared__ float wsum[TPB / 64];

    const int b = blockIdx.x;
    const int t = threadIdx.x;

    // zero state
    for (int i = t; i < DIM; i += TPB) st[i] = make_float2(0.f, 0.f);

    // gate matrices
    if (t < NQ) {
        float th = 0.5f * x[b * NQ + t];
        float c = cosf(th), s = sinf(th);
        R[t][0] = make_float2(c, 0.f);
        R[t][1] = make_float2(0.f, -s);
        R[t][2] = make_float2(0.f, -s);
        R[t][3] = make_float2(c, 0.f);
    }
    if (t >= 64 && t < 64 + NL * NQ) {
        int g = t - 64;
        float phi = wts[g * 3 + 0];
        float th  = wts[g * 3 + 1];
        float om  = wts[g * 3 + 2];
        float c = cosf(0.5f * th), s = sinf(0.5f * th);
        float aa = 0.5f * (phi + om), dd = 0.5f * (phi - om);
        float ca = cosf(aa), sa = sinf(aa);
        float cd = cosf(dd), sd = sinf(dd);
        U[g][0] = make_float2( ca * c, -sa * c);
        U[g][1] = make_float2(-cd * s, -sd * s);
        U[g][2] = make_float2( cd * s, -sd * s);
        U[g][3] = make_float2( ca * c,  sa * c);
    }
    __syncthreads();

    // fold RX into layer-0 Rot: U0 = Rot * RX
    if (t < NQ) {
        float2 a00 = U[t][0], a01 = U[t][1], a10 = U[t][2], a11 = U[t][3];
        float2 b00 = R[t][0], b01 = R[t][1], b10 = R[t][2], b11 = R[t][3];
        auto cm = [](float2 p, float2 q) {
            return make_float2(p.x * q.x - p.y * q.y, p.x * q.y + p.y * q.x);
        };
        auto ca2 = [](float2 p, float2 q) { return make_float2(p.x + q.x, p.y + q.y); };
        U[t][0] = ca2(cm(a00, b00), cm(a01, b10));
        U[t][1] = ca2(cm(a00, b01), cm(a01, b11));
        U[t][2] = ca2(cm(a10, b00), cm(a11, b10));
        U[t][3] = ca2(cm(a10, b01), cm(a11, b11));
    }
    if (t == 0) st[0] = make_float2(1.f, 0.f);   // swz(0)==0
    __syncthreads();

    // ---- 6 layers x 3 fused passes; entangler folded into pass-2 write ----
    for (int l = 0; l < NL; ++l) {
        doPass<0>(st, U, l, t, nullptr, nullptr);
        __syncthreads();
        doPass<1>(st, U, l, t, nullptr, nullptr);
        __syncthreads();
        doPass<2>(st, U, l, t, dT.Wt[l], dT.Wk[l]);
        __syncthreads();
    }

    // ---- fused expectation + FC (storage identity-mapped, swizzled) ----
    float fw[NQ];
#pragma unroll
    for (int w = 0; w < NQ; ++w) fw[w] = fcw[w];

    // wires 0..8 live on h bits 13..5 = t bits 8..0 (pass-0 coset shape)
    float gl = 0.f;
#pragma unroll
    for (int w = 0; w < 9; ++w) gl += ((t >> (8 - w)) & 1) ? -fw[w] : fw[w];

    float acc = 0.f;
#pragma unroll
    for (int k = 0; k < 32; ++k) {
        float2 a = st[haddr<0>(t, k)];
        float p = a.x * a.x + a.y * a.y;
        float g = gl;
#pragma unroll
        for (int w = 9; w < NQ; ++w)
            g += ((k >> (13 - w)) & 1) ? -fw[w] : fw[w];
        acc = fmaf(p, g, acc);
    }

#pragma unroll
    for (int off = 32; off > 0; off >>= 1) acc += __shfl_down(acc, off, 64);
    if ((t & 63) == 0) wsum[t >> 6] = acc;
    __syncthreads();
    if (t == 0) {
        float s = 0.f;
#pragma unroll
        for (int wv = 0; wv < TPB / 64; ++wv) s += wsum[wv];
        out[b] = s + fcb[0];
    }
}

extern "C" void kernel_launch(void* const* d_in, const int* in_sizes, int n_in,
                              void* d_out, int out_size, void* d_ws, size_t ws_size,
                              hipStream_t stream)
{
    const float* x   = (const float*)d_in[0];   // (512, 14)
    const float* wts = (const float*)d_in[1];   // (6, 14, 3)
    const float* fcw = (const float*)d_in[2];   // (1, 14)
    const float* fcb = (const float*)d_in[3];   // (1,)
    float* out = (float*)d_out;                 // (512,)

    const int batch = in_sizes[0] / NQ;         // 512
    const size_t lds_bytes = (size_t)DIM * sizeof(float2);  // 131072

    static bool attr_set = false;
    if (!attr_set) {
        (void)hipFuncSetAttribute((const void*)qc_kernel,
                                  hipFuncAttributeMaxDynamicSharedMemorySize,
                                  (int)lds_bytes);
        attr_set = true;
    }

    qc_kernel<<<batch, TPB, lds_bytes, stream>>>(x, wts, fcw, fcb, out);
}

// Round 4
// 436.961 us; speedup vs baseline: 2.2774x; 1.0003x over previous
//
#include <hip/hip_runtime.h>

#define NQ 14
#define NL 6
#define DIM (1 << NQ)   // 16384 amplitudes
#define TPB 512

// ---------------------------------------------------------------------------
// One block (512 thr) per sample; state in 128 KiB dynamic LDS (swizzled).
// 3 fused passes per layer (5+5+4 gate bits), 32 amps in registers per thread.
// The CNOT entangler layer is a GF(2)-linear index permutation folded into
// pass-2's writeback via compile-time tables (verified exact, absmax 0.0).
// NOTE: 128 KiB dynamic LDS => only 1 block/CU can be resident, so
// __launch_bounds__(TPB, 1): asking for 2 blocks/CU (round 3) capped VGPRs
// at 128 and spilled ~433 MB/dispatch to scratch for zero occupancy gain.
// ---------------------------------------------------------------------------
struct Tbl {
    unsigned short Wt[NL][TPB];
    unsigned short Wk[NL][32];
};

constexpr Tbl buildTbl() {
    Tbl T{};
    for (int l = 0; l < NL; ++l) {
        const int rng = l + 1;   // entangler range r = (l % (NQ-1)) + 1
        unsigned short col[NQ] = {};
        for (int p = 0; p < NQ; ++p) col[p] = (unsigned short)(1 << p);
        for (int w = 0; w < NQ; ++w) {
            int c = NQ - 1 - w;
            int g = NQ - 1 - ((w + rng) % NQ);
            col[c] ^= col[g];
        }
        unsigned int M[NQ] = {}, Inv[NQ] = {};
        for (int q = 0; q < NQ; ++q) {
            M[q] = 0;
            for (int p = 0; p < NQ; ++p) M[q] |= (unsigned)((col[p] >> q) & 1) << p;
            Inv[q] = 1u << q;
        }
        for (int cp = 0; cp < NQ; ++cp) {
            int piv = cp;
            while (!((M[piv] >> cp) & 1)) ++piv;
            unsigned tmp = M[piv]; M[piv] = M[cp]; M[cp] = tmp;
            tmp = Inv[piv]; Inv[piv] = Inv[cp]; Inv[cp] = tmp;
            for (int q = 0; q < NQ; ++q)
                if (q != cp && ((M[q] >> cp) & 1)) { M[q] ^= M[cp]; Inv[q] ^= Inv[cp]; }
        }
        unsigned short colInv[NQ] = {};
        for (int p = 0; p < NQ; ++p) {
            unsigned short v = 0;
            for (int q = 0; q < NQ; ++q) v |= (unsigned short)(((Inv[q] >> p) & 1) << q);
            colInv[p] = v;
        }
        // pass-2 coset shapes (TPB=512, 32 amps):
        //   t bits 0..3 -> h bits 0..3, t bits 4..8 -> h bits 5..9
        //   k bit 0 -> h bit 4, k bits 1..4 -> h bits 10..13
        for (int t = 0; t < TPB; ++t) {
            int ht = (t & 15) | (((t >> 4) & 31) << 5);
            int r2 = 0;
            for (int p = 0; p < NQ; ++p) if ((ht >> p) & 1) r2 ^= colInv[p];
            T.Wt[l][t] = (unsigned short)(r2 ^ ((r2 >> 6) & 63));
        }
        for (int k = 0; k < 32; ++k) {
            int hk = ((k & 1) << 4) | ((k >> 1) << 10);
            int r2 = 0;
            for (int p = 0; p < NQ; ++p) if ((hk >> p) & 1) r2 ^= colInv[p];
            T.Wk[l][k] = (unsigned short)(r2 ^ ((r2 >> 6) & 63));
        }
    }
    return T;
}

__device__ const Tbl dT = buildTbl();

__device__ __forceinline__ int swz(int h) { return h ^ ((h >> 6) & 63); }

template <int S>
__device__ __forceinline__ int haddr(int t, int k) {
    int h;
    if constexpr (S == 0) {
        h = (t << 5) | k;                                        // k -> bits 0..4
    } else if constexpr (S == 1) {
        h = (t & 31) | (k << 5) | ((t >> 5) << 10);              // k -> bits 5..9
    } else {
        h = (t & 15) | (((t >> 4) & 31) << 5)
          | ((k & 1) << 4) | ((k >> 1) << 10);                   // k bits 1..4 -> 10..13
    }
    return swz(h);
}

__device__ __forceinline__ void gate2(float2 u0, float2 u1, float2 u2, float2 u3,
                                      float2& A, float2& C) {
    float2 a = A, c = C, na, nc;
    na.x = u0.x * a.x - u0.y * a.y + u1.x * c.x - u1.y * c.y;
    na.y = u0.x * a.y + u0.y * a.x + u1.x * c.y + u1.y * c.x;
    nc.x = u2.x * a.x - u2.y * a.y + u3.x * c.x - u3.y * c.y;
    nc.y = u2.x * a.y + u2.y * a.x + u3.x * c.y + u3.y * c.x;
    A = na; C = nc;
}

template <int S>
__device__ __forceinline__ void doPass(float2* st, const float2 (*U)[4], int l, int t,
                                       const unsigned short* wt, const unsigned short* wk) {
    float2 r[32];
#pragma unroll
    for (int k = 0; k < 32; ++k) r[k] = st[haddr<S>(t, k)];

    if constexpr (S == 2) __syncthreads();   // all reads done before permuted writes

    constexpr int NG = (S == 2) ? 4 : 5;
#pragma unroll
    for (int jj = 0; jj < NG; ++jj) {
        const int j = (S == 2) ? (jj + 1) : jj;                  // k-bit of this gate
        const int w = (S == 0) ? (13 - jj) : ((S == 1) ? (8 - jj) : (3 - jj));
        const float2* u = U[l * NQ + w];
        float2 u0 = u[0], u1 = u[1], u2 = u[2], u3 = u[3];
#pragma unroll
        for (int m = 0; m < 16; ++m) {
            const int k0 = ((m >> j) << (j + 1)) | (m & ((1 << j) - 1));
            gate2(u0, u1, u2, u3, r[k0], r[k0 | (1 << j)]);
        }
    }

    if constexpr (S == 2) {
        const int at = wt[t];
#pragma unroll
        for (int k = 0; k < 32; ++k) st[at ^ wk[k]] = r[k];
    } else {
#pragma unroll
        for (int k = 0; k < 32; ++k) st[haddr<S>(t, k)] = r[k];
    }
}

__global__ __launch_bounds__(TPB, 1)
void qc_kernel(const float* __restrict__ x,
               const float* __restrict__ wts,
               const float* __restrict__ fcw,
               const float* __restrict__ fcb,
               float* __restrict__ out)
{
    extern __shared__ float2 st[];           // DIM float2 = 128 KiB (swizzled layout)
    __shared__ float2 U[NL * NQ][4];         // Rot (layer0: Rot*RX) matrices
    __shared__ float2 R[NQ][4];              // RX matrices (temp)
    __shared__ float wsum[TPB / 64];

    const int b = blockIdx.x;
    const int t = threadIdx.x;

    // zero state
    for (int i = t; i < DIM; i += TPB) st[i] = make_float2(0.f, 0.f);

    // gate matrices
    if (t < NQ) {
        float th = 0.5f * x[b * NQ + t];
        float c = cosf(th), s = sinf(th);
        R[t][0] = make_float2(c, 0.f);
        R[t][1] = make_float2(0.f, -s);
        R[t][2] = make_float2(0.f, -s);
        R[t][3] = make_float2(c, 0.f);
    }
    if (t >= 64 && t < 64 + NL * NQ) {
        int g = t - 64;
        float phi = wts[g * 3 + 0];
        float th  = wts[g * 3 + 1];
        float om  = wts[g * 3 + 2];
        float c = cosf(0.5f * th), s = sinf(0.5f * th);
        float aa = 0.5f * (phi + om), dd = 0.5f * (phi - om);
        float ca = cosf(aa), sa = sinf(aa);
        float cd = cosf(dd), sd = sinf(dd);
        U[g][0] = make_float2( ca * c, -sa * c);
        U[g][1] = make_float2(-cd * s, -sd * s);
        U[g][2] = make_float2( cd * s, -sd * s);
        U[g][3] = make_float2( ca * c,  sa * c);
    }
    __syncthreads();

    // fold RX into layer-0 Rot: U0 = Rot * RX
    if (t < NQ) {
        float2 a00 = U[t][0], a01 = U[t][1], a10 = U[t][2], a11 = U[t][3];
        float2 b00 = R[t][0], b01 = R[t][1], b10 = R[t][2], b11 = R[t][3];
        auto cm = [](float2 p, float2 q) {
            return make_float2(p.x * q.x - p.y * q.y, p.x * q.y + p.y * q.x);
        };
        auto ca2 = [](float2 p, float2 q) { return make_float2(p.x + q.x, p.y + q.y); };
        U[t][0] = ca2(cm(a00, b00), cm(a01, b10));
        U[t][1] = ca2(cm(a00, b01), cm(a01, b11));
        U[t][2] = ca2(cm(a10, b00), cm(a11, b10));
        U[t][3] = ca2(cm(a10, b01), cm(a11, b11));
    }
    if (t == 0) st[0] = make_float2(1.f, 0.f);   // swz(0)==0
    __syncthreads();

    // ---- 6 layers x 3 fused passes; entangler folded into pass-2 write ----
    for (int l = 0; l < NL; ++l) {
        doPass<0>(st, U, l, t, nullptr, nullptr);
        __syncthreads();
        doPass<1>(st, U, l, t, nullptr, nullptr);
        __syncthreads();
        doPass<2>(st, U, l, t, dT.Wt[l], dT.Wk[l]);
        __syncthreads();
    }

    // ---- fused expectation + FC (storage identity-mapped, swizzled) ----
    float fw[NQ];
#pragma unroll
    for (int w = 0; w < NQ; ++w) fw[w] = fcw[w];

    // wires 0..8 live on h bits 13..5 = t bits 8..0 (pass-0 coset shape)
    float gl = 0.f;
#pragma unroll
    for (int w = 0; w < 9; ++w) gl += ((t >> (8 - w)) & 1) ? -fw[w] : fw[w];

    float acc = 0.f;
#pragma unroll
    for (int k = 0; k < 32; ++k) {
        float2 a = st[haddr<0>(t, k)];
        float p = a.x * a.x + a.y * a.y;
        float g = gl;
#pragma unroll
        for (int w = 9; w < NQ; ++w)
            g += ((k >> (13 - w)) & 1) ? -fw[w] : fw[w];
        acc = fmaf(p, g, acc);
    }

#pragma unroll
    for (int off = 32; off > 0; off >>= 1) acc += __shfl_down(acc, off, 64);
    if ((t & 63) == 0) wsum[t >> 6] = acc;
    __syncthreads();
    if (t == 0) {
        float s = 0.f;
#pragma unroll
        for (int wv = 0; wv < TPB / 64; ++wv) s += wsum[wv];
        out[b] = s + fcb[0];
    }
}

extern "C" void kernel_launch(void* const* d_in, const int* in_sizes, int n_in,
                              void* d_out, int out_size, void* d_ws, size_t ws_size,
                              hipStream_t stream)
{
    const float* x   = (const float*)d_in[0];   // (512, 14)
    const float* wts = (const float*)d_in[1];   // (6, 14, 3)
    const float* fcw = (const float*)d_in[2];   // (1, 14)
    const float* fcb = (const float*)d_in[3];   // (1,)
    float* out = (float*)d_out;                 // (512,)

    const int batch = in_sizes[0] / NQ;         // 512
    const size_t lds_bytes = (size_t)DIM * sizeof(float2);  // 131072

    static bool attr_set = false;
    if (!attr_set) {
        (void)hipFuncSetAttribute((const void*)qc_kernel,
                                  hipFuncAttributeMaxDynamicSharedMemorySize,
                                  (int)lds_bytes);
        attr_set = true;
    }

    qc_kernel<<<batch, TPB, lds_bytes, stream>>>(x, wts, fcw, fcb, out);
}

// Round 5
// 333.695 us; speedup vs baseline: 2.9821x; 1.3095x over previous
//
#include <hip/hip_runtime.h>

#define NQ 14
#define NL 6
#define DIM (1 << NQ)   // 16384 amplitudes
#define TPB 512

// ---------------------------------------------------------------------------
// One block (512 thr) per sample; state in 128 KiB dynamic LDS (swizzled).
// Layer 0 is a product state (RX+Rot are single-qubit): computed directly in
// registers and written through the layer-0 entangler permutation (no init,
// no RMW). Layers 1..5: 3 fused passes (5+5+4 gate bits), 32 amps/thread in
// registers; each layer's CNOT entangler is a GF(2)-linear index permutation
// folded into pass-2's writeback via compile-time tables (verified exact).
//
// amdgpu_waves_per_eu(2,2): 128 KiB dynamic LDS => exactly 1 block/CU =
// 2 waves/SIMD. The backend can't see dynamic LDS and otherwise targets
// 4 waves/EU => 128-VGPR budget => spills r[32] (~433 MB/dispatch scratch
// in rounds 3/4). Clamping desired occupancy to 2 gives the 256-VGPR budget.
// ---------------------------------------------------------------------------
struct Tbl {
    unsigned short Wt[NL][TPB];
    unsigned short Wk[NL][32];
};

constexpr Tbl buildTbl() {
    Tbl T{};
    for (int l = 0; l < NL; ++l) {
        const int rng = l + 1;   // entangler range r = (l % (NQ-1)) + 1
        unsigned short col[NQ] = {};
        for (int p = 0; p < NQ; ++p) col[p] = (unsigned short)(1 << p);
        for (int w = 0; w < NQ; ++w) {
            int c = NQ - 1 - w;
            int g = NQ - 1 - ((w + rng) % NQ);
            col[c] ^= col[g];
        }
        unsigned int M[NQ] = {}, Inv[NQ] = {};
        for (int q = 0; q < NQ; ++q) {
            M[q] = 0;
            for (int p = 0; p < NQ; ++p) M[q] |= (unsigned)((col[p] >> q) & 1) << p;
            Inv[q] = 1u << q;
        }
        for (int cp = 0; cp < NQ; ++cp) {
            int piv = cp;
            while (!((M[piv] >> cp) & 1)) ++piv;
            unsigned tmp = M[piv]; M[piv] = M[cp]; M[cp] = tmp;
            tmp = Inv[piv]; Inv[piv] = Inv[cp]; Inv[cp] = tmp;
            for (int q = 0; q < NQ; ++q)
                if (q != cp && ((M[q] >> cp) & 1)) { M[q] ^= M[cp]; Inv[q] ^= Inv[cp]; }
        }
        unsigned short colInv[NQ] = {};
        for (int p = 0; p < NQ; ++p) {
            unsigned short v = 0;
            for (int q = 0; q < NQ; ++q) v |= (unsigned short)(((Inv[q] >> p) & 1) << q);
            colInv[p] = v;
        }
        // pass-2 coset shapes (TPB=512, 32 amps):
        //   t bits 0..3 -> h bits 0..3, t bits 4..8 -> h bits 5..9
        //   k bit 0 -> h bit 4, k bits 1..4 -> h bits 10..13
        for (int t = 0; t < TPB; ++t) {
            int ht = (t & 15) | (((t >> 4) & 31) << 5);
            int r2 = 0;
            for (int p = 0; p < NQ; ++p) if ((ht >> p) & 1) r2 ^= colInv[p];
            T.Wt[l][t] = (unsigned short)(r2 ^ ((r2 >> 6) & 63));
        }
        for (int k = 0; k < 32; ++k) {
            int hk = ((k & 1) << 4) | ((k >> 1) << 10);
            int r2 = 0;
            for (int p = 0; p < NQ; ++p) if ((hk >> p) & 1) r2 ^= colInv[p];
            T.Wk[l][k] = (unsigned short)(r2 ^ ((r2 >> 6) & 63));
        }
    }
    return T;
}

__device__ const Tbl dT = buildTbl();

__device__ __forceinline__ int swz(int h) { return h ^ ((h >> 6) & 63); }

__device__ __forceinline__ float2 cmul(float2 a, float2 b) {
    return make_float2(a.x * b.x - a.y * b.y, a.x * b.y + a.y * b.x);
}

template <int S>
__device__ __forceinline__ int haddr(int t, int k) {
    int h;
    if constexpr (S == 0) {
        h = (t << 5) | k;                                        // k -> bits 0..4
    } else if constexpr (S == 1) {
        h = (t & 31) | (k << 5) | ((t >> 5) << 10);              // k -> bits 5..9
    } else {
        h = (t & 15) | (((t >> 4) & 31) << 5)
          | ((k & 1) << 4) | ((k >> 1) << 10);                   // k bits 1..4 -> 10..13
    }
    return swz(h);
}

__device__ __forceinline__ void gate2(float2 u0, float2 u1, float2 u2, float2 u3,
                                      float2& A, float2& C) {
    float2 a = A, c = C, na, nc;
    na.x = u0.x * a.x - u0.y * a.y + u1.x * c.x - u1.y * c.y;
    na.y = u0.x * a.y + u0.y * a.x + u1.x * c.y + u1.y * c.x;
    nc.x = u2.x * a.x - u2.y * a.y + u3.x * c.x - u3.y * c.y;
    nc.y = u2.x * a.y + u2.y * a.x + u3.x * c.y + u3.y * c.x;
    A = na; C = nc;
}

template <int S>
__device__ __forceinline__ void doPass(float2* st, const float2 (*U)[4], int l, int t,
                                       const unsigned short* wt, const unsigned short* wk) {
    float2 r[32];
#pragma unroll
    for (int k = 0; k < 32; ++k) r[k] = st[haddr<S>(t, k)];

    if constexpr (S == 2) __syncthreads();   // all reads done before permuted writes

    constexpr int NG = (S == 2) ? 4 : 5;
#pragma unroll
    for (int jj = 0; jj < NG; ++jj) {
        const int j = (S == 2) ? (jj + 1) : jj;                  // k-bit of this gate
        const int w = (S == 0) ? (13 - jj) : ((S == 1) ? (8 - jj) : (3 - jj));
        const float2* u = U[l * NQ + w];
        float2 u0 = u[0], u1 = u[1], u2 = u[2], u3 = u[3];
#pragma unroll
        for (int m = 0; m < 16; ++m) {
            const int k0 = ((m >> j) << (j + 1)) | (m & ((1 << j) - 1));
            gate2(u0, u1, u2, u3, r[k0], r[k0 | (1 << j)]);
        }
    }

    if constexpr (S == 2) {
        const int at = wt[t];
#pragma unroll
        for (int k = 0; k < 32; ++k) st[at ^ wk[k]] = r[k];
    } else {
#pragma unroll
        for (int k = 0; k < 32; ++k) st[haddr<S>(t, k)] = r[k];
    }
}

__global__ __launch_bounds__(TPB) __attribute__((amdgpu_waves_per_eu(2, 2)))
void qc_kernel(const float* __restrict__ x,
               const float* __restrict__ wts,
               const float* __restrict__ fcw,
               const float* __restrict__ fcb,
               float* __restrict__ out)
{
    extern __shared__ float2 st[];           // DIM float2 = 128 KiB (swizzled layout)
    __shared__ float2 U[NL * NQ][4];         // Rot (layer0: Rot*RX) matrices
    __shared__ float2 R[NQ][4];              // RX matrices (temp)
    __shared__ float wsum[TPB / 64];

    const int b = blockIdx.x;
    const int t = threadIdx.x;

    // gate matrices
    if (t < NQ) {
        float th = 0.5f * x[b * NQ + t];
        float c = cosf(th), s = sinf(th);
        R[t][0] = make_float2(c, 0.f);
        R[t][1] = make_float2(0.f, -s);
        R[t][2] = make_float2(0.f, -s);
        R[t][3] = make_float2(c, 0.f);
    }
    if (t >= 64 && t < 64 + NL * NQ) {
        int g = t - 64;
        float phi = wts[g * 3 + 0];
        float th  = wts[g * 3 + 1];
        float om  = wts[g * 3 + 2];
        float c = cosf(0.5f * th), s = sinf(0.5f * th);
        float aa = 0.5f * (phi + om), dd = 0.5f * (phi - om);
        float ca = cosf(aa), sa = sinf(aa);
        float cd = cosf(dd), sd = sinf(dd);
        U[g][0] = make_float2( ca * c, -sa * c);
        U[g][1] = make_float2(-cd * s, -sd * s);
        U[g][2] = make_float2( cd * s, -sd * s);
        U[g][3] = make_float2( ca * c,  sa * c);
    }
    __syncthreads();

    // fold RX into layer-0 Rot: U0 = Rot * RX
    if (t < NQ) {
        float2 a00 = U[t][0], a01 = U[t][1], a10 = U[t][2], a11 = U[t][3];
        float2 b00 = R[t][0], b01 = R[t][1], b10 = R[t][2], b11 = R[t][3];
        auto ca2 = [](float2 p, float2 q) { return make_float2(p.x + q.x, p.y + q.y); };
        U[t][0] = ca2(cmul(a00, b00), cmul(a01, b10));
        U[t][1] = ca2(cmul(a00, b01), cmul(a01, b11));
        U[t][2] = ca2(cmul(a10, b00), cmul(a11, b10));
        U[t][3] = ca2(cmul(a10, b01), cmul(a11, b11));
    }
    __syncthreads();

    // ---- layer 0: product state (Rot*RX)|0> written through entangler-0 ----
    // amp(h) = prod_p cv[p][h_p], cv[p][bb] = column-0 entry bb of wire 13-p.
    {
        float2 A = make_float2(1.f, 0.f);
#pragma unroll
        for (int i = 0; i < 4; ++i) {            // h bit i = t bit i
            float2 v0 = U[13 - i][0], v1 = U[13 - i][2];
            A = cmul(A, ((t >> i) & 1) ? v1 : v0);
        }
#pragma unroll
        for (int i = 0; i < 5; ++i) {            // h bit 5+i = t bit 4+i
            float2 v0 = U[13 - (5 + i)][0], v1 = U[13 - (5 + i)][2];
            A = cmul(A, ((t >> (4 + i)) & 1) ? v1 : v0);
        }
        const int at = dT.Wt[0][t];
        const float2 w4_0 = U[13 - 4][0], w4_1 = U[13 - 4][2];
#pragma unroll
        for (int k4 = 0; k4 < 16; ++k4) {        // h bits 10..13 = k bits 1..4
            float2 C = A;
#pragma unroll
            for (int i = 0; i < 4; ++i) {
                float2 v0 = U[13 - (10 + i)][0], v1 = U[13 - (10 + i)][2];
                C = cmul(C, ((k4 >> i) & 1) ? v1 : v0);
            }
            st[at ^ dT.Wk[0][(k4 << 1) | 0]] = cmul(C, w4_0);
            st[at ^ dT.Wk[0][(k4 << 1) | 1]] = cmul(C, w4_1);
        }
    }
    __syncthreads();

    // ---- layers 1..5: 3 fused passes; entangler folded into pass-2 write ----
    for (int l = 1; l < NL; ++l) {
        doPass<0>(st, U, l, t, nullptr, nullptr);
        __syncthreads();
        doPass<1>(st, U, l, t, nullptr, nullptr);
        __syncthreads();
        doPass<2>(st, U, l, t, dT.Wt[l], dT.Wk[l]);
        __syncthreads();
    }

    // ---- fused expectation + FC (storage identity-mapped, swizzled) ----
    float fw[NQ];
#pragma unroll
    for (int w = 0; w < NQ; ++w) fw[w] = fcw[w];

    // wires 0..8 live on h bits 13..5 = t bits 8..0 (pass-0 coset shape)
    float gl = 0.f;
#pragma unroll
    for (int w = 0; w < 9; ++w) gl += ((t >> (8 - w)) & 1) ? -fw[w] : fw[w];

    float acc = 0.f;
#pragma unroll
    for (int k = 0; k < 32; ++k) {
        float2 a = st[haddr<0>(t, k)];
        float p = a.x * a.x + a.y * a.y;
        float g = gl;
#pragma unroll
        for (int w = 9; w < NQ; ++w)
            g += ((k >> (13 - w)) & 1) ? -fw[w] : fw[w];
        acc = fmaf(p, g, acc);
    }

#pragma unroll
    for (int off = 32; off > 0; off >>= 1) acc += __shfl_down(acc, off, 64);
    if ((t & 63) == 0) wsum[t >> 6] = acc;
    __syncthreads();
    if (t == 0) {
        float s = 0.f;
#pragma unroll
        for (int wv = 0; wv < TPB / 64; ++wv) s += wsum[wv];
        out[b] = s + fcb[0];
    }
}

extern "C" void kernel_launch(void* const* d_in, const int* in_sizes, int n_in,
                              void* d_out, int out_size, void* d_ws, size_t ws_size,
                              hipStream_t stream)
{
    const float* x   = (const float*)d_in[0];   // (512, 14)
    const float* wts = (const float*)d_in[1];   // (6, 14, 3)
    const float* fcw = (const float*)d_in[2];   // (1, 14)
    const float* fcb = (const float*)d_in[3];   // (1,)
    float* out = (float*)d_out;                 // (512,)

    const int batch = in_sizes[0] / NQ;         // 512
    const size_t lds_bytes = (size_t)DIM * sizeof(float2);  // 131072

    static bool attr_set = false;
    if (!attr_set) {
        (void)hipFuncSetAttribute((const void*)qc_kernel,
                                  hipFuncAttributeMaxDynamicSharedMemorySize,
                                  (int)lds_bytes);
        attr_set = true;
    }

    qc_kernel<<<batch, TPB, lds_bytes, stream>>>(x, wts, fcw, fcb, out);
}